// Round 5
// baseline (1123.219 us; speedup 1.0000x reference)
//
#include <hip/hip_runtime.h>
#include <hip/hip_bf16.h>
#include <math.h>

// Problem constants
#define N_NODES 50000
#define E_EDGES 500000
#define G_GRAPHS 128
#define N_PAD 50176   // 196*256, padded node count for scan
// H = 256, NF = 64, EDGE_IN = 905 (rows: hi 0..255 | hj 256..511 | lat 512..520 | fd 521..904)

typedef _Float16 f16;
typedef _Float16 half8 __attribute__((ext_vector_type(8)));
typedef float f32x4 __attribute__((ext_vector_type(4)));

__device__ __forceinline__ float fast_silu(float x) {
    return x * (1.0f / (1.0f + __expf(-x)));
}

// ---------------------------------------------------------------------------
// Pack a [K x 256] row-major fp32 weight into MFMA-B fragment-linear f16.
// chunk (nb, kstep): lane holds B[k=kstep*32+(lane>>4)*8+j][n=nb*16+(lane&15)]
// ---------------------------------------------------------------------------
__global__ void pack_weight(const float* __restrict__ src, f16* __restrict__ dst, int Ksteps) {
    int tid = blockIdx.x * 256 + threadIdx.x;
    int lane = tid & 63;
    int chunk = tid >> 6;
    int kstep = chunk % Ksteps;
    int nb = chunk / Ksteps;
    if (nb >= 16) return;
    int n = nb * 16 + (lane & 15);
    int k0 = kstep * 32 + (lane >> 4) * 8;
    f16* d = dst + (size_t)tid * 8;
#pragma unroll
    for (int j = 0; j < 8; ++j)
        d[j] = (f16)src[(size_t)(k0 + j) * 256 + n];
}

// ---------------------------------------------------------------------------
// latW16[g][n] = f16( eb1[n] + sum_{i,j} (L L^T)[i][j] * eW1[512+i*3+j][n] )
// ---------------------------------------------------------------------------
__global__ void prep_latw(const float* __restrict__ lat, const float* __restrict__ eW1,
                          const float* __restrict__ eb1, f16* __restrict__ latW16) {
    int g = blockIdx.x, n = threadIdx.x;
    float l[9];
#pragma unroll
    for (int i = 0; i < 9; ++i) l[i] = lat[g * 9 + i];
    float acc = eb1[n];
#pragma unroll
    for (int i = 0; i < 3; ++i)
#pragma unroll
        for (int j = 0; j < 3; ++j) {
            float ip = l[i*3+0]*l[j*3+0] + l[i*3+1]*l[j*3+1] + l[i*3+2]*l[j*3+2];
            acc += ip * eW1[(size_t)(512 + i*3 + j) * 256 + n];
        }
    latW16[g * 256 + n] = (f16)acc;
}

// ---------------------------------------------------------------------------
// CSR build: histogram -> single-block scan -> position scatter
// ---------------------------------------------------------------------------
__global__ void hist_kernel(const int* __restrict__ ei, int* __restrict__ cnt) {
    int e = blockIdx.x * 256 + threadIdx.x;
    if (e < E_EDGES) atomicAdd(cnt + ei[e], 1);
}

__global__ __launch_bounds__(1024) void scan_kernel(const int* __restrict__ cnt, int* __restrict__ off) {
    __shared__ int wsum[16], wpre[16];
    __shared__ int stot;
    int t = threadIdx.x, lane = t & 63, w = t >> 6;
    int running = 0;
    for (int c = 0; c < N_PAD; c += 1024) {
        int v = cnt[c + t];
        int x = v;
#pragma unroll
        for (int d = 1; d < 64; d <<= 1) { int nn = __shfl_up(x, d); if (lane >= d) x += nn; }
        if (lane == 63) wsum[w] = x;
        __syncthreads();
        if (t == 0) { int a = 0; for (int i = 0; i < 16; ++i) { wpre[i] = a; a += wsum[i]; } stot = a; }
        __syncthreads();
        off[c + t] = running + wpre[w] + x - v;   // exclusive
        running += stot;
        __syncthreads();
    }
}

__global__ void pos_kernel(const int* __restrict__ ei, const int* __restrict__ off,
                           int* __restrict__ tmp, int* __restrict__ sorted_e) {
    int e = blockIdx.x * 256 + threadIdx.x;
    if (e >= E_EDGES) return;
    int s = ei[e];
    int p = off[s] + atomicAdd(tmp + s, 1);
    sorted_e[p] = e;
}

// ---------------------------------------------------------------------------
// LayerNorm(h) then three GEMMs -> f16 outputs Hh1/Hh2/Nh
// ---------------------------------------------------------------------------
__global__ __launch_bounds__(256) void ln_gemm_kernel(
    const float* __restrict__ h, const float* __restrict__ gamma, const float* __restrict__ beta,
    const f16* __restrict__ Whi, const f16* __restrict__ Whj, const f16* __restrict__ Wn1,
    f16* __restrict__ Hh1, f16* __restrict__ Hh2, f16* __restrict__ Nh)
{
    __shared__ f16 Aln[64 * 264];
    int tid = threadIdx.x;
    int r = tid >> 2, c4 = tid & 3;
    int row = blockIdx.x * 64 + r;
    int rowc = min(row, N_NODES - 1);
    const float* hp = h + (size_t)rowc * 256 + c4 * 64;

    float v[64];
    float s = 0.f, ss = 0.f;
#pragma unroll
    for (int i = 0; i < 16; ++i) {
        float4 x = ((const float4*)hp)[i];
        v[4*i+0] = x.x; v[4*i+1] = x.y; v[4*i+2] = x.z; v[4*i+3] = x.w;
        s  += x.x + x.y + x.z + x.w;
        ss += x.x*x.x + x.y*x.y + x.z*x.z + x.w*x.w;
    }
    s += __shfl_xor(s, 1); ss += __shfl_xor(ss, 1);
    s += __shfl_xor(s, 2); ss += __shfl_xor(ss, 2);
    float mean = s * (1.f / 256.f);
    float var  = ss * (1.f / 256.f) - mean * mean;
    float rstd = rsqrtf(var + 1e-5f);

    const float* gp = gamma + c4 * 64;
    const float* bp = beta + c4 * 64;
    f16 lnv[64];
#pragma unroll
    for (int i = 0; i < 16; ++i) {
        float4 g = ((const float4*)gp)[i];
        float4 b = ((const float4*)bp)[i];
        lnv[4*i+0] = (f16)((v[4*i+0]-mean)*rstd*g.x + b.x);
        lnv[4*i+1] = (f16)((v[4*i+1]-mean)*rstd*g.y + b.y);
        lnv[4*i+2] = (f16)((v[4*i+2]-mean)*rstd*g.z + b.z);
        lnv[4*i+3] = (f16)((v[4*i+3]-mean)*rstd*g.w + b.w);
    }
    {
        f16* dp = Aln + r * 264 + c4 * 64;
#pragma unroll
        for (int i = 0; i < 8; ++i) ((half8*)dp)[i] = ((half8*)lnv)[i];
    }
    __syncthreads();

    int lane = tid & 63, w = tid >> 6;
    int l15 = lane & 15, q = lane >> 4;
    const f16* Ws[3] = {Whi, Whj, Wn1};
    f16* Os[3] = {Hh1, Hh2, Nh};
    const f32x4 z4 = {0.f, 0.f, 0.f, 0.f};

    for (int widx = 0; widx < 3; ++widx) {
        f32x4 acc[4][4];
#pragma unroll
        for (int a = 0; a < 4; ++a)
#pragma unroll
            for (int b = 0; b < 4; ++b) acc[a][b] = z4;
        const f16* W = Ws[widx];
        for (int ks = 0; ks < 8; ++ks) {
            half8 afr[4];
#pragma unroll
            for (int mb = 0; mb < 4; ++mb)
                afr[mb] = *(const half8*)(Aln + (mb*16 + l15) * 264 + ks*32 + q*8);
#pragma unroll
            for (int nbl = 0; nbl < 4; ++nbl) {
                int nb = w * 4 + nbl;
                half8 bfr = *(const half8*)(W + ((size_t)(nb*8 + ks) * 64 + lane) * 8);
#pragma unroll
                for (int mb = 0; mb < 4; ++mb)
                    acc[mb][nbl] = __builtin_amdgcn_mfma_f32_16x16x32_f16(afr[mb], bfr, acc[mb][nbl], 0, 0, 0);
            }
        }
        f16* O = Os[widx];
#pragma unroll
        for (int mb = 0; mb < 4; ++mb)
#pragma unroll
            for (int rr = 0; rr < 4; ++rr) {
                int orow = blockIdx.x * 64 + mb*16 + q*4 + rr;
                if (orow < N_NODES) {
#pragma unroll
                    for (int nbl = 0; nbl < 4; ++nbl) {
                        int n = (w*4 + nbl) * 16 + l15;
                        O[(size_t)orow * 256 + n] = (f16)acc[mb][nbl][rr];
                    }
                }
            }
    }
}

// ---------------------------------------------------------------------------
// Edge kernel v5: v4 structure, NO min-waves cap (R3/R4 caps forced AGPR
// spill to scratch: WRITE_SIZE 1.9/1.2 GB; R2's plain (256) had 57 MB).
// Single acc[][] reused for both GEMMs to halve AGPR pressure (~64 not 128).
// ---------------------------------------------------------------------------
__global__ __launch_bounds__(256) void edge_kernel(
    const int* __restrict__ sorted_e,
    const int* __restrict__ edge_index, const int* __restrict__ edge2graph,
    const float* __restrict__ frac_diff,
    const f16* __restrict__ Hh1, const f16* __restrict__ Hh2, const f16* __restrict__ latW16,
    const f16* __restrict__ Wfd, const f16* __restrict__ We2, const float* __restrict__ eb2,
    float* __restrict__ aggsum)
{
    __shared__ f16 buf[64 * 264];                 // 33.8 KB: R tile -> e1 tile -> e2 tile
    __shared__ float frac_s[64][4];               // padded
    __shared__ int src_s[64], dst_s[64], g_s[64], srcr[64];
    int tid = threadIdx.x;
    int e0 = blockIdx.x * 64;

    if (tid < 64) {
        int slot = e0 + tid;
        int e = (slot < E_EDGES) ? sorted_e[slot] : -1;
        int ec = e < 0 ? 0 : e;
        int sv = edge_index[ec];
        src_s[tid] = sv;
        dst_s[tid] = edge_index[E_EDGES + ec];
        g_s[tid]   = edge2graph[ec];
        srcr[tid]  = (e < 0) ? -1 : sv;
        frac_s[tid][0] = frac_diff[(size_t)ec * 3 + 0];
        frac_s[tid][1] = frac_diff[(size_t)ec * 3 + 1];
        frac_s[tid][2] = frac_diff[(size_t)ec * 3 + 2];
    }
    __syncthreads();   // B1: indices + frac ready

    // ---- R-fill: R[m][n] = Hh1[src]+Hh2[dst]+latW[g], wide f16 loads + pk adds
    {
        int rbase = tid >> 5;          // 0..7
        int cc = tid & 31;             // 16B chunk in row
#pragma unroll
        for (int i = 0; i < 8; ++i) {
            int m = i * 8 + rbase;
            half8 a = *(const half8*)(Hh1   + (size_t)src_s[m] * 256 + cc * 8);
            half8 b = *(const half8*)(Hh2   + (size_t)dst_s[m] * 256 + cc * 8);
            half8 c = *(const half8*)(latW16 + (size_t)g_s[m] * 256 + cc * 8);
            half8 rsum = a + b + c;
            *(half8*)(buf + m * 264 + cc * 8) = rsum;
        }
    }
    __syncthreads();   // B2: R tile ready

    int lane = tid & 63, w = tid >> 6;
    int l15 = lane & 15, q = lane >> 4;

    // per-lane frac values for its 4 A-rows (mb*16 + l15), all 3 dims
    float xr[4][3];
#pragma unroll
    for (int mb = 0; mb < 4; ++mb)
#pragma unroll
        for (int d = 0; d < 3; ++d)
            xr[mb][d] = frac_s[mb*16 + l15][d];
    float fq = (float)(8 * q);

    // ---- acc init = R (MFMA C-init trick): read own C-layout elements from buf
    f32x4 acc[4][4];
#pragma unroll
    for (int mb = 0; mb < 4; ++mb)
#pragma unroll
        for (int rr = 0; rr < 4; ++rr) {
            int mm = mb*16 + q*4 + rr;
#pragma unroll
            for (int nbl = 0; nbl < 4; ++nbl) {
                int n = (w*4 + nbl) * 16 + l15;
                acc[mb][nbl][rr] = (float)buf[mm * 264 + n];
            }
        }

    // ---- GEMM1: fd_emb [64 x 384] @ Wfd [384 x 256], A computed in-register.
    // k = ks*32 + q*8 + j; ks<6 -> sin block (d=ks/2, fbase=(ks&1)*32), else cos.
#pragma unroll
    for (int ks = 0; ks < 12; ++ks) {
        const int kk = (ks < 6) ? ks : ks - 6;
        const int d = kk >> 1;
        const float fbase = (float)((kk & 1) * 32);
        half8 bfr[4];
#pragma unroll
        for (int nbl = 0; nbl < 4; ++nbl)
            bfr[nbl] = *(const half8*)(Wfd + ((size_t)((w*4 + nbl)*12 + ks) * 64 + lane) * 8);
        float fj[8];
#pragma unroll
        for (int j = 0; j < 8; ++j) fj[j] = fbase + (float)j + fq;
#pragma unroll
        for (int mb = 0; mb < 4; ++mb) {
            float x = xr[mb][d];
            f16 av[8];
#pragma unroll
            for (int j = 0; j < 8; ++j) {
                float t = x * fj[j];
                float rev = t - floorf(t);
                float vv = (ks < 6) ? __builtin_amdgcn_sinf(rev) : __builtin_amdgcn_cosf(rev);
                av[j] = (f16)vv;
            }
            half8 afr = *(half8*)av;
#pragma unroll
            for (int nbl = 0; nbl < 4; ++nbl)
                acc[mb][nbl] = __builtin_amdgcn_mfma_f32_16x16x32_f16(afr, bfr[nbl], acc[mb][nbl], 0, 0, 0);
        }
    }

    // ---- epilogue 1: silu -> e1 tile in-place (owner-exclusive elements)
#pragma unroll
    for (int mb = 0; mb < 4; ++mb)
#pragma unroll
        for (int rr = 0; rr < 4; ++rr) {
            int mm = mb*16 + q*4 + rr;
#pragma unroll
            for (int nbl = 0; nbl < 4; ++nbl) {
                int n = (w*4 + nbl) * 16 + l15;
                buf[mm * 264 + n] = (f16)fast_silu(acc[mb][nbl][rr]);
            }
        }
    __syncthreads();   // B3: e1 tile ready

    // preload eb2 values for this thread's columns
    float eb2v[4];
#pragma unroll
    for (int nbl = 0; nbl < 4; ++nbl)
        eb2v[nbl] = eb2[(w*4 + nbl) * 16 + l15];

    // ---- GEMM2: [64 x 256] @ [256 x 256] -- REUSE acc (AGPR liveness share)
    const f32x4 z4 = {0.f, 0.f, 0.f, 0.f};
#pragma unroll
    for (int a = 0; a < 4; ++a)
#pragma unroll
        for (int b = 0; b < 4; ++b) acc[a][b] = z4;
#pragma unroll
    for (int ks = 0; ks < 8; ++ks) {
        half8 afr[4];
#pragma unroll
        for (int mb = 0; mb < 4; ++mb)
            afr[mb] = *(const half8*)(buf + (mb*16 + l15) * 264 + ks*32 + q*8);
#pragma unroll
        for (int nbl = 0; nbl < 4; ++nbl) {
            half8 bfr = *(const half8*)(We2 + ((size_t)((w*4 + nbl)*8 + ks) * 64 + lane) * 8);
#pragma unroll
            for (int mb = 0; mb < 4; ++mb)
                acc[mb][nbl] = __builtin_amdgcn_mfma_f32_16x16x32_f16(afr[mb], bfr, acc[mb][nbl], 0, 0, 0);
        }
    }
    __syncthreads();   // B4: all e1 reads done before overwrite

    // ---- epilogue 2: silu(+eb2) -> e2 tile (zeros for invalid slots)
#pragma unroll
    for (int mb = 0; mb < 4; ++mb)
#pragma unroll
        for (int rr = 0; rr < 4; ++rr) {
            int mm = mb*16 + q*4 + rr;
            bool valid = (srcr[mm] >= 0);
#pragma unroll
            for (int nbl = 0; nbl < 4; ++nbl) {
                int n = (w*4 + nbl) * 16 + l15;
                float vv = valid ? fast_silu(acc[mb][nbl][rr] + eb2v[nbl]) : 0.f;
                buf[mm * 264 + n] = (f16)vv;
            }
        }
    __syncthreads();   // B5: e2 tile ready

    // ---- segmented reduction: thread t owns column t; src runs contiguous
    {
        int t = tid;
        float run = 0.f;
        int cur = srcr[0];
        for (int mm = 0; mm < 64; ++mm) {
            int s = srcr[mm];
            float v = (float)buf[mm * 264 + t];
            if (s != cur) {
                if (cur >= 0) atomicAdd(aggsum + (size_t)cur * 256 + t, run);
                cur = s; run = v;
            } else run += v;
        }
        if (cur >= 0) atomicAdd(aggsum + (size_t)cur * 256 + t, run);
    }
}

// ---------------------------------------------------------------------------
// Node post: agg = aggsum / max(cnt,1); t = silu(Nh + agg@Wn1a + nb1);
// out = h + silu(t@Wn2 + nb2)
// ---------------------------------------------------------------------------
__global__ __launch_bounds__(256) void node_post_kernel(
    const float* __restrict__ aggsum, const int* __restrict__ cnt,
    const f16* __restrict__ Nh, const f16* __restrict__ Wn1a, const f16* __restrict__ Wn2,
    const float* __restrict__ nb1, const float* __restrict__ nb2,
    const float* __restrict__ h, float* __restrict__ out)
{
    __shared__ f16 T[64 * 264];
    int tid = threadIdx.x;
    int r = tid >> 2, c4 = tid & 3;
    int row = blockIdx.x * 64 + r;
    int rowc = min(row, N_NODES - 1);
    float inv = 1.f / fmaxf((float)cnt[rowc], 1.f);
    {
        const float* ap = aggsum + (size_t)rowc * 256 + c4 * 64;
        f16 av[64];
#pragma unroll
        for (int i = 0; i < 16; ++i) {
            float4 x = ((const float4*)ap)[i];
            av[4*i+0] = (f16)(x.x * inv);
            av[4*i+1] = (f16)(x.y * inv);
            av[4*i+2] = (f16)(x.z * inv);
            av[4*i+3] = (f16)(x.w * inv);
        }
        f16* dp = T + r * 264 + c4 * 64;
#pragma unroll
        for (int i = 0; i < 8; ++i) ((half8*)dp)[i] = ((half8*)av)[i];
    }
    __syncthreads();

    int lane = tid & 63, w = tid >> 6;
    int l15 = lane & 15, q = lane >> 4;
    const f32x4 z4 = {0.f, 0.f, 0.f, 0.f};

    f32x4 acc[4][4];
#pragma unroll
    for (int a = 0; a < 4; ++a)
#pragma unroll
        for (int b = 0; b < 4; ++b) acc[a][b] = z4;
    for (int ks = 0; ks < 8; ++ks) {
        half8 afr[4];
#pragma unroll
        for (int mb = 0; mb < 4; ++mb)
            afr[mb] = *(const half8*)(T + (mb*16 + l15) * 264 + ks*32 + q*8);
#pragma unroll
        for (int nbl = 0; nbl < 4; ++nbl) {
            int nb = w * 4 + nbl;
            half8 bfr = *(const half8*)(Wn1a + ((size_t)(nb*8 + ks) * 64 + lane) * 8);
#pragma unroll
            for (int mb = 0; mb < 4; ++mb)
                acc[mb][nbl] = __builtin_amdgcn_mfma_f32_16x16x32_f16(afr[mb], bfr, acc[mb][nbl], 0, 0, 0);
        }
    }
    __syncthreads();

#pragma unroll
    for (int mb = 0; mb < 4; ++mb)
#pragma unroll
        for (int rr = 0; rr < 4; ++rr) {
            int orow = blockIdx.x * 64 + mb*16 + q*4 + rr;
            int orc = min(orow, N_NODES - 1);
            const f16* np = Nh + (size_t)orc * 256;
            int mm = mb*16 + q*4 + rr;
#pragma unroll
            for (int nbl = 0; nbl < 4; ++nbl) {
                int n = (w*4 + nbl) * 16 + l15;
                float tv = fast_silu(acc[mb][nbl][rr] + (float)np[n] + nb1[n]);
                T[mm * 264 + n] = (f16)tv;
            }
        }
    __syncthreads();

    f32x4 acc2[4][4];
#pragma unroll
    for (int a = 0; a < 4; ++a)
#pragma unroll
        for (int b = 0; b < 4; ++b) acc2[a][b] = z4;
    for (int ks = 0; ks < 8; ++ks) {
        half8 afr[4];
#pragma unroll
        for (int mb = 0; mb < 4; ++mb)
            afr[mb] = *(const half8*)(T + (mb*16 + l15) * 264 + ks*32 + q*8);
#pragma unroll
        for (int nbl = 0; nbl < 4; ++nbl) {
            int nb = w * 4 + nbl;
            half8 bfr = *(const half8*)(Wn2 + ((size_t)(nb*8 + ks) * 64 + lane) * 8);
#pragma unroll
            for (int mb = 0; mb < 4; ++mb)
                acc2[mb][nbl] = __builtin_amdgcn_mfma_f32_16x16x32_f16(afr[mb], bfr, acc2[mb][nbl], 0, 0, 0);
        }
    }

#pragma unroll
    for (int mb = 0; mb < 4; ++mb)
#pragma unroll
        for (int rr = 0; rr < 4; ++rr) {
            int orow = blockIdx.x * 64 + mb*16 + q*4 + rr;
            if (orow < N_NODES) {
#pragma unroll
                for (int nbl = 0; nbl < 4; ++nbl) {
                    int n = (w*4 + nbl) * 16 + l15;
                    float ov = h[(size_t)orow * 256 + n] + fast_silu(acc2[mb][nbl][rr] + nb2[n]);
                    out[(size_t)orow * 256 + n] = ov;
                }
            }
        }
}

// ---------------------------------------------------------------------------
extern "C" void kernel_launch(void* const* d_in, const int* in_sizes, int n_in,
                              void* d_out, int out_size, void* d_ws, size_t ws_size,
                              hipStream_t stream) {
    const float* h          = (const float*)d_in[0];
    const float* lattices   = (const float*)d_in[2];
    const int*   edge_index = (const int*)d_in[3];
    const int*   edge2graph = (const int*)d_in[4];
    const float* frac_diff  = (const float*)d_in[5];
    const float* ln_gamma   = (const float*)d_in[6];
    const float* ln_beta    = (const float*)d_in[7];
    const float* eW1        = (const float*)d_in[8];
    const float* eb1        = (const float*)d_in[9];
    const float* eW2        = (const float*)d_in[10];
    const float* eb2        = (const float*)d_in[11];
    const float* nW1        = (const float*)d_in[12];
    const float* nb1        = (const float*)d_in[13];
    const float* nW2        = (const float*)d_in[14];
    const float* nb2        = (const float*)d_in[15];
    float* out = (float*)d_out;
    char* base = (char*)d_ws;

    // workspace layout (byte offsets)
    float* aggsum   = (float*)(base + 0);              // 51,200,000 B
    int*   cnt      = (int*)  (base + 51200000);       // 200,704
    int*   off      = (int*)  (base + 51400704);       // 200,704
    int*   tmp      = (int*)  (base + 51601408);       // 200,704
    int*   sorted_e = (int*)  (base + 51802112);       // 2,000,000
    f16*   latW16   = (f16*)  (base + 53802112);       // 65,536
    f16*   Hh1      = (f16*)  (base + 53867648);       // 25,600,000
    f16*   Hh2      = (f16*)  (base + 79467648);
    f16*   Nh       = (f16*)  (base + 105067648);
    f16*   packs    = (f16*)  (base + 130667648);
    f16* Wfd  = packs;            // 98,304 halfs (K=384)
    f16* Whi  = Wfd  + 98304;
    f16* Whj  = Whi  + 65536;
    f16* We2  = Whj  + 65536;
    f16* Wn1h = We2  + 65536;
    f16* Wn1a = Wn1h + 65536;
    f16* Wn2  = Wn1a + 65536;     // ends at byte 131,650,688
    if (ws_size < (size_t)131650688) return;

    // zero aggsum + cnt + off + tmp
    hipMemsetAsync(base, 0, (size_t)51802112, stream);

    pack_weight<<<48, 256, 0, stream>>>(eW1 + 521 * 256, Wfd, 12);
    pack_weight<<<32, 256, 0, stream>>>(eW1,             Whi, 8);
    pack_weight<<<32, 256, 0, stream>>>(eW1 + 256 * 256, Whj, 8);
    pack_weight<<<32, 256, 0, stream>>>(eW2,             We2, 8);
    pack_weight<<<32, 256, 0, stream>>>(nW1,             Wn1h, 8);
    pack_weight<<<32, 256, 0, stream>>>(nW1 + 256 * 256, Wn1a, 8);
    pack_weight<<<32, 256, 0, stream>>>(nW2,             Wn2, 8);
    prep_latw<<<G_GRAPHS, 256, 0, stream>>>(lattices, eW1, eb1, latW16);

    hist_kernel<<<(E_EDGES + 255) / 256, 256, 0, stream>>>(edge_index, cnt);
    scan_kernel<<<1, 1024, 0, stream>>>(cnt, off);
    pos_kernel<<<(E_EDGES + 255) / 256, 256, 0, stream>>>(edge_index, off, tmp, sorted_e);

    ln_gemm_kernel<<<(N_NODES + 63) / 64, 256, 0, stream>>>(
        h, ln_gamma, ln_beta, Whi, Whj, Wn1h, Hh1, Hh2, Nh);

    edge_kernel<<<(E_EDGES + 63) / 64, 256, 0, stream>>>(
        sorted_e, edge_index, edge2graph, frac_diff, Hh1, Hh2, latW16, Wfd, We2, eb2, aggsum);

    node_post_kernel<<<(N_NODES + 63) / 64, 256, 0, stream>>>(
        aggsum, cnt, Nh, Wn1a, Wn2, nb1, nb2, h, out);
}

// Round 6
// 851.957 us; speedup vs baseline: 1.3184x; 1.3184x over previous
//
#include <hip/hip_runtime.h>
#include <hip/hip_bf16.h>
#include <math.h>

// Problem constants
#define N_NODES 50000
#define E_EDGES 500000
#define G_GRAPHS 128
#define N_PAD 50176   // 196*256, padded node count for scan
// H = 256, NF = 64, EDGE_IN = 905 (rows: hi 0..255 | hj 256..511 | lat 512..520 | fd 521..904)

typedef _Float16 f16;
typedef _Float16 half8 __attribute__((ext_vector_type(8)));
typedef float f32x4 __attribute__((ext_vector_type(4)));

__device__ __forceinline__ float fast_silu(float x) {
    return x * (1.0f / (1.0f + __expf(-x)));
}

// ---------------------------------------------------------------------------
// Pack a [K x 256] row-major fp32 weight into MFMA-B fragment-linear f16.
// chunk (nb, kstep): lane holds B[k=kstep*32+(lane>>4)*8+j][n=nb*16+(lane&15)]
// ---------------------------------------------------------------------------
__global__ void pack_weight(const float* __restrict__ src, f16* __restrict__ dst, int Ksteps) {
    int tid = blockIdx.x * 256 + threadIdx.x;
    int lane = tid & 63;
    int chunk = tid >> 6;
    int kstep = chunk % Ksteps;
    int nb = chunk / Ksteps;
    if (nb >= 16) return;
    int n = nb * 16 + (lane & 15);
    int k0 = kstep * 32 + (lane >> 4) * 8;
    f16* d = dst + (size_t)tid * 8;
#pragma unroll
    for (int j = 0; j < 8; ++j)
        d[j] = (f16)src[(size_t)(k0 + j) * 256 + n];
}

// ---------------------------------------------------------------------------
// latW16[g][n] = f16( eb1[n] + sum_{i,j} (L L^T)[i][j] * eW1[512+i*3+j][n] )
// ---------------------------------------------------------------------------
__global__ void prep_latw(const float* __restrict__ lat, const float* __restrict__ eW1,
                          const float* __restrict__ eb1, f16* __restrict__ latW16) {
    int g = blockIdx.x, n = threadIdx.x;
    float l[9];
#pragma unroll
    for (int i = 0; i < 9; ++i) l[i] = lat[g * 9 + i];
    float acc = eb1[n];
#pragma unroll
    for (int i = 0; i < 3; ++i)
#pragma unroll
        for (int j = 0; j < 3; ++j) {
            float ip = l[i*3+0]*l[j*3+0] + l[i*3+1]*l[j*3+1] + l[i*3+2]*l[j*3+2];
            acc += ip * eW1[(size_t)(512 + i*3 + j) * 256 + n];
        }
    latW16[g * 256 + n] = (f16)acc;
}

// ---------------------------------------------------------------------------
// CSR build: histogram -> single-block scan -> position scatter
// ---------------------------------------------------------------------------
__global__ void hist_kernel(const int* __restrict__ ei, int* __restrict__ cnt) {
    int e = blockIdx.x * 256 + threadIdx.x;
    if (e < E_EDGES) atomicAdd(cnt + ei[e], 1);
}

__global__ __launch_bounds__(1024) void scan_kernel(const int* __restrict__ cnt, int* __restrict__ off) {
    __shared__ int wsum[16], wpre[16];
    __shared__ int stot;
    int t = threadIdx.x, lane = t & 63, w = t >> 6;
    int running = 0;
    for (int c = 0; c < N_PAD; c += 1024) {
        int v = cnt[c + t];
        int x = v;
#pragma unroll
        for (int d = 1; d < 64; d <<= 1) { int nn = __shfl_up(x, d); if (lane >= d) x += nn; }
        if (lane == 63) wsum[w] = x;
        __syncthreads();
        if (t == 0) { int a = 0; for (int i = 0; i < 16; ++i) { wpre[i] = a; a += wsum[i]; } stot = a; }
        __syncthreads();
        off[c + t] = running + wpre[w] + x - v;   // exclusive
        running += stot;
        __syncthreads();
    }
}

__global__ void pos_kernel(const int* __restrict__ ei, const int* __restrict__ off,
                           int* __restrict__ tmp, int* __restrict__ sorted_e) {
    int e = blockIdx.x * 256 + threadIdx.x;
    if (e >= E_EDGES) return;
    int s = ei[e];
    int p = off[s] + atomicAdd(tmp + s, 1);
    sorted_e[p] = e;
}

// ---------------------------------------------------------------------------
// LayerNorm(h) then three GEMMs -> f16 outputs Hh1/Hh2/Nh
// ---------------------------------------------------------------------------
__global__ __launch_bounds__(256) void ln_gemm_kernel(
    const float* __restrict__ h, const float* __restrict__ gamma, const float* __restrict__ beta,
    const f16* __restrict__ Whi, const f16* __restrict__ Whj, const f16* __restrict__ Wn1,
    f16* __restrict__ Hh1, f16* __restrict__ Hh2, f16* __restrict__ Nh)
{
    __shared__ f16 Aln[64 * 264];
    int tid = threadIdx.x;
    int r = tid >> 2, c4 = tid & 3;
    int row = blockIdx.x * 64 + r;
    int rowc = min(row, N_NODES - 1);
    const float* hp = h + (size_t)rowc * 256 + c4 * 64;

    float v[64];
    float s = 0.f, ss = 0.f;
#pragma unroll
    for (int i = 0; i < 16; ++i) {
        float4 x = ((const float4*)hp)[i];
        v[4*i+0] = x.x; v[4*i+1] = x.y; v[4*i+2] = x.z; v[4*i+3] = x.w;
        s  += x.x + x.y + x.z + x.w;
        ss += x.x*x.x + x.y*x.y + x.z*x.z + x.w*x.w;
    }
    s += __shfl_xor(s, 1); ss += __shfl_xor(ss, 1);
    s += __shfl_xor(s, 2); ss += __shfl_xor(ss, 2);
    float mean = s * (1.f / 256.f);
    float var  = ss * (1.f / 256.f) - mean * mean;
    float rstd = rsqrtf(var + 1e-5f);

    const float* gp = gamma + c4 * 64;
    const float* bp = beta + c4 * 64;
    f16 lnv[64];
#pragma unroll
    for (int i = 0; i < 16; ++i) {
        float4 g = ((const float4*)gp)[i];
        float4 b = ((const float4*)bp)[i];
        lnv[4*i+0] = (f16)((v[4*i+0]-mean)*rstd*g.x + b.x);
        lnv[4*i+1] = (f16)((v[4*i+1]-mean)*rstd*g.y + b.y);
        lnv[4*i+2] = (f16)((v[4*i+2]-mean)*rstd*g.z + b.z);
        lnv[4*i+3] = (f16)((v[4*i+3]-mean)*rstd*g.w + b.w);
    }
    {
        f16* dp = Aln + r * 264 + c4 * 64;
#pragma unroll
        for (int i = 0; i < 8; ++i) ((half8*)dp)[i] = ((half8*)lnv)[i];
    }
    __syncthreads();

    int lane = tid & 63, w = tid >> 6;
    int l15 = lane & 15, q = lane >> 4;
    const f16* Ws[3] = {Whi, Whj, Wn1};
    f16* Os[3] = {Hh1, Hh2, Nh};
    const f32x4 z4 = {0.f, 0.f, 0.f, 0.f};

    for (int widx = 0; widx < 3; ++widx) {
        f32x4 acc[4][4];
#pragma unroll
        for (int a = 0; a < 4; ++a)
#pragma unroll
            for (int b = 0; b < 4; ++b) acc[a][b] = z4;
        const f16* W = Ws[widx];
        for (int ks = 0; ks < 8; ++ks) {
            half8 afr[4];
#pragma unroll
            for (int mb = 0; mb < 4; ++mb)
                afr[mb] = *(const half8*)(Aln + (mb*16 + l15) * 264 + ks*32 + q*8);
#pragma unroll
            for (int nbl = 0; nbl < 4; ++nbl) {
                int nb = w * 4 + nbl;
                half8 bfr = *(const half8*)(W + ((size_t)(nb*8 + ks) * 64 + lane) * 8);
#pragma unroll
                for (int mb = 0; mb < 4; ++mb)
                    acc[mb][nbl] = __builtin_amdgcn_mfma_f32_16x16x32_f16(afr[mb], bfr, acc[mb][nbl], 0, 0, 0);
            }
        }
        f16* O = Os[widx];
#pragma unroll
        for (int mb = 0; mb < 4; ++mb)
#pragma unroll
            for (int rr = 0; rr < 4; ++rr) {
                int orow = blockIdx.x * 64 + mb*16 + q*4 + rr;
                if (orow < N_NODES) {
#pragma unroll
                    for (int nbl = 0; nbl < 4; ++nbl) {
                        int n = (w*4 + nbl) * 16 + l15;
                        O[(size_t)orow * 256 + n] = (f16)acc[mb][nbl][rr];
                    }
                }
            }
    }
}

// ---------------------------------------------------------------------------
// Edge kernel v6: M=32 edges/block (register-pressure fix). The fused M=64
// tile needs ~300 regs/thread: capped -> spill storm (R3/R4), uncapped ->
// 1 block/CU (R5). M=32 halves acc (32 AGPR peak), sin work, and R-fill per
// thread; (256,3) cap=170 >> demand ~130 -> no spill, 3 blocks/CU.
// ---------------------------------------------------------------------------
__global__ __launch_bounds__(256, 3) void edge_kernel(
    const int* __restrict__ sorted_e,
    const int* __restrict__ edge_index, const int* __restrict__ edge2graph,
    const float* __restrict__ frac_diff,
    const f16* __restrict__ Hh1, const f16* __restrict__ Hh2, const f16* __restrict__ latW16,
    const f16* __restrict__ Wfd, const f16* __restrict__ We2, const float* __restrict__ eb2,
    float* __restrict__ aggsum)
{
    __shared__ f16 buf[32 * 264];                 // 16.9 KB: R tile -> e1 tile
    __shared__ f16 buf2[32 * 264];                // 16.9 KB: e2 tile (separate -> one fewer barrier)
    __shared__ float frac_s[32][4];
    __shared__ int src_s[32], dst_s[32], g_s[32], srcr[32];
    int tid = threadIdx.x;
    int e0 = blockIdx.x * 32;

    if (tid < 32) {
        int slot = e0 + tid;
        int e = (slot < E_EDGES) ? sorted_e[slot] : -1;
        int ec = e < 0 ? 0 : e;
        int sv = edge_index[ec];
        src_s[tid] = sv;
        dst_s[tid] = edge_index[E_EDGES + ec];
        g_s[tid]   = edge2graph[ec];
        srcr[tid]  = (e < 0) ? -1 : sv;
        frac_s[tid][0] = frac_diff[(size_t)ec * 3 + 0];
        frac_s[tid][1] = frac_diff[(size_t)ec * 3 + 1];
        frac_s[tid][2] = frac_diff[(size_t)ec * 3 + 2];
    }
    __syncthreads();   // B1: indices + frac ready

    // ---- R-fill: R[m][n] = Hh1[src]+Hh2[dst]+latW[g]; 32 rows x 32 chunks
#pragma unroll
    for (int i = 0; i < 4; ++i) {
        int idx = i * 256 + tid;
        int m = idx >> 5;              // 0..31
        int cc = idx & 31;             // 16B chunk in row
        half8 a = *(const half8*)(Hh1    + (size_t)src_s[m] * 256 + cc * 8);
        half8 b = *(const half8*)(Hh2    + (size_t)dst_s[m] * 256 + cc * 8);
        half8 c = *(const half8*)(latW16 + (size_t)g_s[m]  * 256 + cc * 8);
        half8 rsum = a + b + c;
        *(half8*)(buf + m * 264 + cc * 8) = rsum;
    }
    __syncthreads();   // B2: R tile ready

    int lane = tid & 63, w = tid >> 6;
    int l15 = lane & 15, q = lane >> 4;

    // per-lane frac values for its 2 A-rows (mb*16 + l15), all 3 dims
    float xr[2][3];
#pragma unroll
    for (int mb = 0; mb < 2; ++mb)
#pragma unroll
        for (int d = 0; d < 3; ++d)
            xr[mb][d] = frac_s[mb*16 + l15][d];
    float fq = (float)(8 * q);

    // ---- acc init = R (MFMA C-init trick)
    f32x4 acc[2][4];
#pragma unroll
    for (int mb = 0; mb < 2; ++mb)
#pragma unroll
        for (int rr = 0; rr < 4; ++rr) {
            int mm = mb*16 + q*4 + rr;
#pragma unroll
            for (int nbl = 0; nbl < 4; ++nbl) {
                int n = (w*4 + nbl) * 16 + l15;
                acc[mb][nbl][rr] = (float)buf[mm * 264 + n];
            }
        }

    // ---- GEMM1: fd_emb [32 x 384] @ Wfd [384 x 256], A computed in-register.
    // k = ks*32 + q*8 + j; ks<6 -> sin block (d=ks/2, fbase=(ks&1)*32), else cos.
#pragma unroll
    for (int ks = 0; ks < 12; ++ks) {
        const int kk = (ks < 6) ? ks : ks - 6;
        const int d = kk >> 1;
        const float fbase = (float)((kk & 1) * 32);
        half8 bfr[4];
#pragma unroll
        for (int nbl = 0; nbl < 4; ++nbl)
            bfr[nbl] = *(const half8*)(Wfd + ((size_t)((w*4 + nbl)*12 + ks) * 64 + lane) * 8);
#pragma unroll
        for (int mb = 0; mb < 2; ++mb) {
            float x = xr[mb][d];
            f16 av[8];
#pragma unroll
            for (int j = 0; j < 8; ++j) {
                float t = x * (fbase + (float)j + fq);
                float rev = t - floorf(t);
                float vv = (ks < 6) ? __builtin_amdgcn_sinf(rev) : __builtin_amdgcn_cosf(rev);
                av[j] = (f16)vv;
            }
            half8 afr = *(half8*)av;
#pragma unroll
            for (int nbl = 0; nbl < 4; ++nbl)
                acc[mb][nbl] = __builtin_amdgcn_mfma_f32_16x16x32_f16(afr, bfr[nbl], acc[mb][nbl], 0, 0, 0);
        }
    }

    // ---- epilogue 1: silu -> e1 tile in-place (owner-exclusive elements)
#pragma unroll
    for (int mb = 0; mb < 2; ++mb)
#pragma unroll
        for (int rr = 0; rr < 4; ++rr) {
            int mm = mb*16 + q*4 + rr;
#pragma unroll
            for (int nbl = 0; nbl < 4; ++nbl) {
                int n = (w*4 + nbl) * 16 + l15;
                buf[mm * 264 + n] = (f16)fast_silu(acc[mb][nbl][rr]);
            }
        }
    __syncthreads();   // B3: e1 tile ready

    // preload eb2 values for this thread's columns
    float eb2v[4];
#pragma unroll
    for (int nbl = 0; nbl < 4; ++nbl)
        eb2v[nbl] = eb2[(w*4 + nbl) * 16 + l15];

    // ---- GEMM2: [32 x 256] @ [256 x 256] -- reuse acc (liveness-disjoint)
    const f32x4 z4 = {0.f, 0.f, 0.f, 0.f};
#pragma unroll
    for (int a = 0; a < 2; ++a)
#pragma unroll
        for (int b = 0; b < 4; ++b) acc[a][b] = z4;
#pragma unroll
    for (int ks = 0; ks < 8; ++ks) {
        half8 afr[2];
#pragma unroll
        for (int mb = 0; mb < 2; ++mb)
            afr[mb] = *(const half8*)(buf + (mb*16 + l15) * 264 + ks*32 + q*8);
#pragma unroll
        for (int nbl = 0; nbl < 4; ++nbl) {
            half8 bfr = *(const half8*)(We2 + ((size_t)((w*4 + nbl)*8 + ks) * 64 + lane) * 8);
#pragma unroll
            for (int mb = 0; mb < 2; ++mb)
                acc[mb][nbl] = __builtin_amdgcn_mfma_f32_16x16x32_f16(afr[mb], bfr, acc[mb][nbl], 0, 0, 0);
        }
    }

    // ---- epilogue 2: silu(+eb2) -> e2 tile in buf2 (zeros for invalid slots)
#pragma unroll
    for (int mb = 0; mb < 2; ++mb)
#pragma unroll
        for (int rr = 0; rr < 4; ++rr) {
            int mm = mb*16 + q*4 + rr;
            bool valid = (srcr[mm] >= 0);
#pragma unroll
            for (int nbl = 0; nbl < 4; ++nbl) {
                int n = (w*4 + nbl) * 16 + l15;
                float vv = valid ? fast_silu(acc[mb][nbl][rr] + eb2v[nbl]) : 0.f;
                buf2[mm * 264 + n] = (f16)vv;
            }
        }
    __syncthreads();   // B4: e2 tile ready

    // ---- segmented reduction: thread t owns column t; src runs contiguous
    {
        int t = tid;
        float run = 0.f;
        int cur = srcr[0];
        for (int mm = 0; mm < 32; ++mm) {
            int s = srcr[mm];
            float v = (float)buf2[mm * 264 + t];
            if (s != cur) {
                if (cur >= 0) atomicAdd(aggsum + (size_t)cur * 256 + t, run);
                cur = s; run = v;
            } else run += v;
        }
        if (cur >= 0) atomicAdd(aggsum + (size_t)cur * 256 + t, run);
    }
}

// ---------------------------------------------------------------------------
// Node post: agg = aggsum / max(cnt,1); t = silu(Nh + agg@Wn1a + nb1);
// out = h + silu(t@Wn2 + nb2)
// ---------------------------------------------------------------------------
__global__ __launch_bounds__(256) void node_post_kernel(
    const float* __restrict__ aggsum, const int* __restrict__ cnt,
    const f16* __restrict__ Nh, const f16* __restrict__ Wn1a, const f16* __restrict__ Wn2,
    const float* __restrict__ nb1, const float* __restrict__ nb2,
    const float* __restrict__ h, float* __restrict__ out)
{
    __shared__ f16 T[64 * 264];
    int tid = threadIdx.x;
    int r = tid >> 2, c4 = tid & 3;
    int row = blockIdx.x * 64 + r;
    int rowc = min(row, N_NODES - 1);
    float inv = 1.f / fmaxf((float)cnt[rowc], 1.f);
    {
        const float* ap = aggsum + (size_t)rowc * 256 + c4 * 64;
        f16 av[64];
#pragma unroll
        for (int i = 0; i < 16; ++i) {
            float4 x = ((const float4*)ap)[i];
            av[4*i+0] = (f16)(x.x * inv);
            av[4*i+1] = (f16)(x.y * inv);
            av[4*i+2] = (f16)(x.z * inv);
            av[4*i+3] = (f16)(x.w * inv);
        }
        f16* dp = T + r * 264 + c4 * 64;
#pragma unroll
        for (int i = 0; i < 8; ++i) ((half8*)dp)[i] = ((half8*)av)[i];
    }
    __syncthreads();

    int lane = tid & 63, w = tid >> 6;
    int l15 = lane & 15, q = lane >> 4;
    const f32x4 z4 = {0.f, 0.f, 0.f, 0.f};

    f32x4 acc[4][4];
#pragma unroll
    for (int a = 0; a < 4; ++a)
#pragma unroll
        for (int b = 0; b < 4; ++b) acc[a][b] = z4;
    for (int ks = 0; ks < 8; ++ks) {
        half8 afr[4];
#pragma unroll
        for (int mb = 0; mb < 4; ++mb)
            afr[mb] = *(const half8*)(T + (mb*16 + l15) * 264 + ks*32 + q*8);
#pragma unroll
        for (int nbl = 0; nbl < 4; ++nbl) {
            int nb = w * 4 + nbl;
            half8 bfr = *(const half8*)(Wn1a + ((size_t)(nb*8 + ks) * 64 + lane) * 8);
#pragma unroll
            for (int mb = 0; mb < 4; ++mb)
                acc[mb][nbl] = __builtin_amdgcn_mfma_f32_16x16x32_f16(afr[mb], bfr, acc[mb][nbl], 0, 0, 0);
        }
    }
    __syncthreads();

#pragma unroll
    for (int mb = 0; mb < 4; ++mb)
#pragma unroll
        for (int rr = 0; rr < 4; ++rr) {
            int orow = blockIdx.x * 64 + mb*16 + q*4 + rr;
            int orc = min(orow, N_NODES - 1);
            const f16* np = Nh + (size_t)orc * 256;
            int mm = mb*16 + q*4 + rr;
#pragma unroll
            for (int nbl = 0; nbl < 4; ++nbl) {
                int n = (w*4 + nbl) * 16 + l15;
                float tv = fast_silu(acc[mb][nbl][rr] + (float)np[n] + nb1[n]);
                T[mm * 264 + n] = (f16)tv;
            }
        }
    __syncthreads();

    f32x4 acc2[4][4];
#pragma unroll
    for (int a = 0; a < 4; ++a)
#pragma unroll
        for (int b = 0; b < 4; ++b) acc2[a][b] = z4;
    for (int ks = 0; ks < 8; ++ks) {
        half8 afr[4];
#pragma unroll
        for (int mb = 0; mb < 4; ++mb)
            afr[mb] = *(const half8*)(T + (mb*16 + l15) * 264 + ks*32 + q*8);
#pragma unroll
        for (int nbl = 0; nbl < 4; ++nbl) {
            int nb = w * 4 + nbl;
            half8 bfr = *(const half8*)(Wn2 + ((size_t)(nb*8 + ks) * 64 + lane) * 8);
#pragma unroll
            for (int mb = 0; mb < 4; ++mb)
                acc2[mb][nbl] = __builtin_amdgcn_mfma_f32_16x16x32_f16(afr[mb], bfr, acc2[mb][nbl], 0, 0, 0);
        }
    }

#pragma unroll
    for (int mb = 0; mb < 4; ++mb)
#pragma unroll
        for (int rr = 0; rr < 4; ++rr) {
            int orow = blockIdx.x * 64 + mb*16 + q*4 + rr;
            if (orow < N_NODES) {
#pragma unroll
                for (int nbl = 0; nbl < 4; ++nbl) {
                    int n = (w*4 + nbl) * 16 + l15;
                    float ov = h[(size_t)orow * 256 + n] + fast_silu(acc2[mb][nbl][rr] + nb2[n]);
                    out[(size_t)orow * 256 + n] = ov;
                }
            }
        }
}

// ---------------------------------------------------------------------------
extern "C" void kernel_launch(void* const* d_in, const int* in_sizes, int n_in,
                              void* d_out, int out_size, void* d_ws, size_t ws_size,
                              hipStream_t stream) {
    const float* h          = (const float*)d_in[0];
    const float* lattices   = (const float*)d_in[2];
    const int*   edge_index = (const int*)d_in[3];
    const int*   edge2graph = (const int*)d_in[4];
    const float* frac_diff  = (const float*)d_in[5];
    const float* ln_gamma   = (const float*)d_in[6];
    const float* ln_beta    = (const float*)d_in[7];
    const float* eW1        = (const float*)d_in[8];
    const float* eb1        = (const float*)d_in[9];
    const float* eW2        = (const float*)d_in[10];
    const float* eb2        = (const float*)d_in[11];
    const float* nW1        = (const float*)d_in[12];
    const float* nb1        = (const float*)d_in[13];
    const float* nW2        = (const float*)d_in[14];
    const float* nb2        = (const float*)d_in[15];
    float* out = (float*)d_out;
    char* base = (char*)d_ws;

    // workspace layout (byte offsets)
    float* aggsum   = (float*)(base + 0);              // 51,200,000 B
    int*   cnt      = (int*)  (base + 51200000);       // 200,704
    int*   off      = (int*)  (base + 51400704);       // 200,704
    int*   tmp      = (int*)  (base + 51601408);       // 200,704
    int*   sorted_e = (int*)  (base + 51802112);       // 2,000,000
    f16*   latW16   = (f16*)  (base + 53802112);       // 65,536
    f16*   Hh1      = (f16*)  (base + 53867648);       // 25,600,000
    f16*   Hh2      = (f16*)  (base + 79467648);
    f16*   Nh       = (f16*)  (base + 105067648);
    f16*   packs    = (f16*)  (base + 130667648);
    f16* Wfd  = packs;            // 98,304 halfs (K=384)
    f16* Whi  = Wfd  + 98304;
    f16* Whj  = Whi  + 65536;
    f16* We2  = Whj  + 65536;
    f16* Wn1h = We2  + 65536;
    f16* Wn1a = Wn1h + 65536;
    f16* Wn2  = Wn1a + 65536;     // ends at byte 131,650,688
    if (ws_size < (size_t)131650688) return;

    // zero aggsum + cnt + off + tmp
    hipMemsetAsync(base, 0, (size_t)51802112, stream);

    pack_weight<<<48, 256, 0, stream>>>(eW1 + 521 * 256, Wfd, 12);
    pack_weight<<<32, 256, 0, stream>>>(eW1,             Whi, 8);
    pack_weight<<<32, 256, 0, stream>>>(eW1 + 256 * 256, Whj, 8);
    pack_weight<<<32, 256, 0, stream>>>(eW2,             We2, 8);
    pack_weight<<<32, 256, 0, stream>>>(nW1,             Wn1h, 8);
    pack_weight<<<32, 256, 0, stream>>>(nW1 + 256 * 256, Wn1a, 8);
    pack_weight<<<32, 256, 0, stream>>>(nW2,             Wn2, 8);
    prep_latw<<<G_GRAPHS, 256, 0, stream>>>(lattices, eW1, eb1, latW16);

    hist_kernel<<<(E_EDGES + 255) / 256, 256, 0, stream>>>(edge_index, cnt);
    scan_kernel<<<1, 1024, 0, stream>>>(cnt, off);
    pos_kernel<<<(E_EDGES + 255) / 256, 256, 0, stream>>>(edge_index, off, tmp, sorted_e);

    ln_gemm_kernel<<<(N_NODES + 63) / 64, 256, 0, stream>>>(
        h, ln_gamma, ln_beta, Whi, Whj, Wn1h, Hh1, Hh2, Nh);

    edge_kernel<<<(E_EDGES + 31) / 32, 256, 0, stream>>>(
        sorted_e, edge_index, edge2graph, frac_diff, Hh1, Hh2, latW16, Wfd, We2, eb2, aggsum);

    node_post_kernel<<<(N_NODES + 63) / 64, 256, 0, stream>>>(
        aggsum, cnt, Nh, Wn1a, Wn2, nb1, nb2, h, out);
}

// Round 7
// 784.679 us; speedup vs baseline: 1.4314x; 1.0857x over previous
//
#include <hip/hip_runtime.h>
#include <hip/hip_bf16.h>
#include <math.h>

// Problem constants
#define N_NODES 50000
#define E_EDGES 500000
#define G_GRAPHS 128
#define N_PAD 50176   // 196*256, padded node count for scan
// H = 256, NF = 64, EDGE_IN = 905 (rows: hi 0..255 | hj 256..511 | lat 512..520 | fd 521..904)

typedef _Float16 f16;
typedef _Float16 half8 __attribute__((ext_vector_type(8)));
typedef float f32x4 __attribute__((ext_vector_type(4)));

__device__ __forceinline__ float fast_silu(float x) {
    return x * (1.0f / (1.0f + __expf(-x)));
}

// ---------------------------------------------------------------------------
// Pack a [K x 256] row-major fp32 weight into MFMA-B fragment-linear f16.
// chunk (nb, kstep): lane holds B[k=kstep*32+(lane>>4)*8+j][n=nb*16+(lane&15)]
// ---------------------------------------------------------------------------
__global__ void pack_weight(const float* __restrict__ src, f16* __restrict__ dst, int Ksteps) {
    int tid = blockIdx.x * 256 + threadIdx.x;
    int lane = tid & 63;
    int chunk = tid >> 6;
    int kstep = chunk % Ksteps;
    int nb = chunk / Ksteps;
    if (nb >= 16) return;
    int n = nb * 16 + (lane & 15);
    int k0 = kstep * 32 + (lane >> 4) * 8;
    f16* d = dst + (size_t)tid * 8;
#pragma unroll
    for (int j = 0; j < 8; ++j)
        d[j] = (f16)src[(size_t)(k0 + j) * 256 + n];
}

// ---------------------------------------------------------------------------
// latW16[g][n] = f16( eb1[n] + sum_{i,j} (L L^T)[i][j] * eW1[512+i*3+j][n] )
// ---------------------------------------------------------------------------
__global__ void prep_latw(const float* __restrict__ lat, const float* __restrict__ eW1,
                          const float* __restrict__ eb1, f16* __restrict__ latW16) {
    int g = blockIdx.x, n = threadIdx.x;
    float l[9];
#pragma unroll
    for (int i = 0; i < 9; ++i) l[i] = lat[g * 9 + i];
    float acc = eb1[n];
#pragma unroll
    for (int i = 0; i < 3; ++i)
#pragma unroll
        for (int j = 0; j < 3; ++j) {
            float ip = l[i*3+0]*l[j*3+0] + l[i*3+1]*l[j*3+1] + l[i*3+2]*l[j*3+2];
            acc += ip * eW1[(size_t)(512 + i*3 + j) * 256 + n];
        }
    latW16[g * 256 + n] = (f16)acc;
}

// ---------------------------------------------------------------------------
// CSR build: histogram -> single-block scan -> position scatter
// ---------------------------------------------------------------------------
__global__ void hist_kernel(const int* __restrict__ ei, int* __restrict__ cnt) {
    int e = blockIdx.x * 256 + threadIdx.x;
    if (e < E_EDGES) atomicAdd(cnt + ei[e], 1);
}

__global__ __launch_bounds__(1024) void scan_kernel(const int* __restrict__ cnt, int* __restrict__ off) {
    __shared__ int wsum[16], wpre[16];
    __shared__ int stot;
    int t = threadIdx.x, lane = t & 63, w = t >> 6;
    int running = 0;
    for (int c = 0; c < N_PAD; c += 1024) {
        int v = cnt[c + t];
        int x = v;
#pragma unroll
        for (int d = 1; d < 64; d <<= 1) { int nn = __shfl_up(x, d); if (lane >= d) x += nn; }
        if (lane == 63) wsum[w] = x;
        __syncthreads();
        if (t == 0) { int a = 0; for (int i = 0; i < 16; ++i) { wpre[i] = a; a += wsum[i]; } stot = a; }
        __syncthreads();
        off[c + t] = running + wpre[w] + x - v;   // exclusive
        running += stot;
        __syncthreads();
    }
}

__global__ void pos_kernel(const int* __restrict__ ei, const int* __restrict__ off,
                           int* __restrict__ tmp, int* __restrict__ sorted_e) {
    int e = blockIdx.x * 256 + threadIdx.x;
    if (e >= E_EDGES) return;
    int s = ei[e];
    int p = off[s] + atomicAdd(tmp + s, 1);
    sorted_e[p] = e;
}

// ---------------------------------------------------------------------------
// LayerNorm(h) then three GEMMs -> f16 outputs Hh1/Hh2/Nh
// ---------------------------------------------------------------------------
__global__ __launch_bounds__(256) void ln_gemm_kernel(
    const float* __restrict__ h, const float* __restrict__ gamma, const float* __restrict__ beta,
    const f16* __restrict__ Whi, const f16* __restrict__ Whj, const f16* __restrict__ Wn1,
    f16* __restrict__ Hh1, f16* __restrict__ Hh2, f16* __restrict__ Nh)
{
    __shared__ f16 Aln[64 * 264];
    int tid = threadIdx.x;
    int r = tid >> 2, c4 = tid & 3;
    int row = blockIdx.x * 64 + r;
    int rowc = min(row, N_NODES - 1);
    const float* hp = h + (size_t)rowc * 256 + c4 * 64;

    float v[64];
    float s = 0.f, ss = 0.f;
#pragma unroll
    for (int i = 0; i < 16; ++i) {
        float4 x = ((const float4*)hp)[i];
        v[4*i+0] = x.x; v[4*i+1] = x.y; v[4*i+2] = x.z; v[4*i+3] = x.w;
        s  += x.x + x.y + x.z + x.w;
        ss += x.x*x.x + x.y*x.y + x.z*x.z + x.w*x.w;
    }
    s += __shfl_xor(s, 1); ss += __shfl_xor(ss, 1);
    s += __shfl_xor(s, 2); ss += __shfl_xor(ss, 2);
    float mean = s * (1.f / 256.f);
    float var  = ss * (1.f / 256.f) - mean * mean;
    float rstd = rsqrtf(var + 1e-5f);

    const float* gp = gamma + c4 * 64;
    const float* bp = beta + c4 * 64;
    f16 lnv[64];
#pragma unroll
    for (int i = 0; i < 16; ++i) {
        float4 g = ((const float4*)gp)[i];
        float4 b = ((const float4*)bp)[i];
        lnv[4*i+0] = (f16)((v[4*i+0]-mean)*rstd*g.x + b.x);
        lnv[4*i+1] = (f16)((v[4*i+1]-mean)*rstd*g.y + b.y);
        lnv[4*i+2] = (f16)((v[4*i+2]-mean)*rstd*g.z + b.z);
        lnv[4*i+3] = (f16)((v[4*i+3]-mean)*rstd*g.w + b.w);
    }
    {
        f16* dp = Aln + r * 264 + c4 * 64;
#pragma unroll
        for (int i = 0; i < 8; ++i) ((half8*)dp)[i] = ((half8*)lnv)[i];
    }
    __syncthreads();

    int lane = tid & 63, w = tid >> 6;
    int l15 = lane & 15, q = lane >> 4;
    const f16* Ws[3] = {Whi, Whj, Wn1};
    f16* Os[3] = {Hh1, Hh2, Nh};
    const f32x4 z4 = {0.f, 0.f, 0.f, 0.f};

    for (int widx = 0; widx < 3; ++widx) {
        f32x4 acc[4][4];
#pragma unroll
        for (int a = 0; a < 4; ++a)
#pragma unroll
            for (int b = 0; b < 4; ++b) acc[a][b] = z4;
        const f16* W = Ws[widx];
        for (int ks = 0; ks < 8; ++ks) {
            half8 afr[4];
#pragma unroll
            for (int mb = 0; mb < 4; ++mb)
                afr[mb] = *(const half8*)(Aln + (mb*16 + l15) * 264 + ks*32 + q*8);
#pragma unroll
            for (int nbl = 0; nbl < 4; ++nbl) {
                int nb = w * 4 + nbl;
                half8 bfr = *(const half8*)(W + ((size_t)(nb*8 + ks) * 64 + lane) * 8);
#pragma unroll
                for (int mb = 0; mb < 4; ++mb)
                    acc[mb][nbl] = __builtin_amdgcn_mfma_f32_16x16x32_f16(afr[mb], bfr, acc[mb][nbl], 0, 0, 0);
            }
        }
        f16* O = Os[widx];
#pragma unroll
        for (int mb = 0; mb < 4; ++mb)
#pragma unroll
            for (int rr = 0; rr < 4; ++rr) {
                int orow = blockIdx.x * 64 + mb*16 + q*4 + rr;
                if (orow < N_NODES) {
#pragma unroll
                    for (int nbl = 0; nbl < 4; ++nbl) {
                        int n = (w*4 + nbl) * 16 + l15;
                        O[(size_t)orow * 256 + n] = (f16)acc[mb][nbl][rr];
                    }
                }
            }
    }
}

// ---------------------------------------------------------------------------
// Edge kernel v7: v6 (M=32) structure + complex-rotation sinusoids.
// sin/cos(2*pi*x*(f0+j)) built by rotating (s,c) by the constant angle 2*pi*x:
// one 8-step chain per (kk,mb) yields BOTH the sin fragment (ks=kk) and the
// cos fragment (ks=kk+6). 36 trans/thread vs 192 direct (5.3x); rotation
// error over 7 steps ~1e-6 << f16 rounding.
// ---------------------------------------------------------------------------
__global__ __launch_bounds__(256, 3) void edge_kernel(
    const int* __restrict__ sorted_e,
    const int* __restrict__ edge_index, const int* __restrict__ edge2graph,
    const float* __restrict__ frac_diff,
    const f16* __restrict__ Hh1, const f16* __restrict__ Hh2, const f16* __restrict__ latW16,
    const f16* __restrict__ Wfd, const f16* __restrict__ We2, const float* __restrict__ eb2,
    float* __restrict__ aggsum)
{
    __shared__ f16 buf[32 * 264];                 // 16.9 KB: R tile -> e1 tile
    __shared__ f16 buf2[32 * 264];                // 16.9 KB: e2 tile
    __shared__ float frac_s[32][4];
    __shared__ int src_s[32], dst_s[32], g_s[32], srcr[32];
    int tid = threadIdx.x;
    int e0 = blockIdx.x * 32;

    if (tid < 32) {
        int slot = e0 + tid;
        int e = (slot < E_EDGES) ? sorted_e[slot] : -1;
        int ec = e < 0 ? 0 : e;
        int sv = edge_index[ec];
        src_s[tid] = sv;
        dst_s[tid] = edge_index[E_EDGES + ec];
        g_s[tid]   = edge2graph[ec];
        srcr[tid]  = (e < 0) ? -1 : sv;
        frac_s[tid][0] = frac_diff[(size_t)ec * 3 + 0];
        frac_s[tid][1] = frac_diff[(size_t)ec * 3 + 1];
        frac_s[tid][2] = frac_diff[(size_t)ec * 3 + 2];
    }
    __syncthreads();   // B1: indices + frac ready

    // ---- R-fill: R[m][n] = Hh1[src]+Hh2[dst]+latW[g]; 32 rows x 32 chunks
#pragma unroll
    for (int i = 0; i < 4; ++i) {
        int idx = i * 256 + tid;
        int m = idx >> 5;              // 0..31
        int cc = idx & 31;             // 16B chunk in row
        half8 a = *(const half8*)(Hh1    + (size_t)src_s[m] * 256 + cc * 8);
        half8 b = *(const half8*)(Hh2    + (size_t)dst_s[m] * 256 + cc * 8);
        half8 c = *(const half8*)(latW16 + (size_t)g_s[m]  * 256 + cc * 8);
        half8 rsum = a + b + c;
        *(half8*)(buf + m * 264 + cc * 8) = rsum;
    }
    __syncthreads();   // B2: R tile ready

    int lane = tid & 63, w = tid >> 6;
    int l15 = lane & 15, q = lane >> 4;

    // per-lane frac values for its 2 A-rows (mb*16 + l15), all 3 dims
    float xr[2][3];
#pragma unroll
    for (int mb = 0; mb < 2; ++mb)
#pragma unroll
        for (int d = 0; d < 3; ++d)
            xr[mb][d] = frac_s[mb*16 + l15][d];
    float fq = (float)(8 * q);

    // rotation constants per (mb,d): angle step = 2*pi*x (x in [0,1) -> rev = x)
    float c1v[2][3], s1v[2][3];
#pragma unroll
    for (int mb = 0; mb < 2; ++mb)
#pragma unroll
        for (int d = 0; d < 3; ++d) {
            float x = xr[mb][d];
            c1v[mb][d] = __builtin_amdgcn_cosf(x);
            s1v[mb][d] = __builtin_amdgcn_sinf(x);
        }

    // ---- acc init = R (MFMA C-init trick)
    f32x4 acc[2][4];
#pragma unroll
    for (int mb = 0; mb < 2; ++mb)
#pragma unroll
        for (int rr = 0; rr < 4; ++rr) {
            int mm = mb*16 + q*4 + rr;
#pragma unroll
            for (int nbl = 0; nbl < 4; ++nbl) {
                int n = (w*4 + nbl) * 16 + l15;
                acc[mb][nbl][rr] = (float)buf[mm * 264 + n];
            }
        }

    // ---- GEMM1: fd_emb [32 x 384] @ Wfd [384 x 256], A by rotation recurrence.
    // k = ks*32 + q*8 + j; ks=kk -> sin(x*(fbase+8q+j)), ks=kk+6 -> cos(same).
#pragma unroll
    for (int kk = 0; kk < 6; ++kk) {
        const int d = kk >> 1;
        const float fbase = (float)((kk & 1) * 32);
        half8 bS[4], bC[4];
#pragma unroll
        for (int nbl = 0; nbl < 4; ++nbl) {
            bS[nbl] = *(const half8*)(Wfd + ((size_t)((w*4 + nbl)*12 + kk)     * 64 + lane) * 8);
            bC[nbl] = *(const half8*)(Wfd + ((size_t)((w*4 + nbl)*12 + kk + 6) * 64 + lane) * 8);
        }
#pragma unroll
        for (int mb = 0; mb < 2; ++mb) {
            float x = xr[mb][d];
            float c1 = c1v[mb][d], s1 = s1v[mb][d];
            float t0 = x * (fbase + fq);
            float rev = t0 - floorf(t0);
            float s = __builtin_amdgcn_sinf(rev);
            float c = __builtin_amdgcn_cosf(rev);
            f16 avs[8], avc[8];
            avs[0] = (f16)s; avc[0] = (f16)c;
#pragma unroll
            for (int j = 1; j < 8; ++j) {
                float ns = s * c1 + c * s1;
                float nc = c * c1 - s * s1;
                s = ns; c = nc;
                avs[j] = (f16)s; avc[j] = (f16)c;
            }
            half8 aS = *(half8*)avs;
            half8 aC = *(half8*)avc;
#pragma unroll
            for (int nbl = 0; nbl < 4; ++nbl) {
                acc[mb][nbl] = __builtin_amdgcn_mfma_f32_16x16x32_f16(aS, bS[nbl], acc[mb][nbl], 0, 0, 0);
                acc[mb][nbl] = __builtin_amdgcn_mfma_f32_16x16x32_f16(aC, bC[nbl], acc[mb][nbl], 0, 0, 0);
            }
        }
    }

    // ---- epilogue 1: silu -> e1 tile in-place (owner-exclusive elements)
#pragma unroll
    for (int mb = 0; mb < 2; ++mb)
#pragma unroll
        for (int rr = 0; rr < 4; ++rr) {
            int mm = mb*16 + q*4 + rr;
#pragma unroll
            for (int nbl = 0; nbl < 4; ++nbl) {
                int n = (w*4 + nbl) * 16 + l15;
                buf[mm * 264 + n] = (f16)fast_silu(acc[mb][nbl][rr]);
            }
        }
    __syncthreads();   // B3: e1 tile ready

    // preload eb2 values for this thread's columns
    float eb2v[4];
#pragma unroll
    for (int nbl = 0; nbl < 4; ++nbl)
        eb2v[nbl] = eb2[(w*4 + nbl) * 16 + l15];

    // ---- GEMM2: [32 x 256] @ [256 x 256] -- reuse acc (liveness-disjoint)
    const f32x4 z4 = {0.f, 0.f, 0.f, 0.f};
#pragma unroll
    for (int a = 0; a < 2; ++a)
#pragma unroll
        for (int b = 0; b < 4; ++b) acc[a][b] = z4;
#pragma unroll
    for (int ks = 0; ks < 8; ++ks) {
        half8 afr[2];
#pragma unroll
        for (int mb = 0; mb < 2; ++mb)
            afr[mb] = *(const half8*)(buf + (mb*16 + l15) * 264 + ks*32 + q*8);
#pragma unroll
        for (int nbl = 0; nbl < 4; ++nbl) {
            half8 bfr = *(const half8*)(We2 + ((size_t)((w*4 + nbl)*8 + ks) * 64 + lane) * 8);
#pragma unroll
            for (int mb = 0; mb < 2; ++mb)
                acc[mb][nbl] = __builtin_amdgcn_mfma_f32_16x16x32_f16(afr[mb], bfr, acc[mb][nbl], 0, 0, 0);
        }
    }

    // ---- epilogue 2: silu(+eb2) -> e2 tile in buf2 (zeros for invalid slots)
#pragma unroll
    for (int mb = 0; mb < 2; ++mb)
#pragma unroll
        for (int rr = 0; rr < 4; ++rr) {
            int mm = mb*16 + q*4 + rr;
            bool valid = (srcr[mm] >= 0);
#pragma unroll
            for (int nbl = 0; nbl < 4; ++nbl) {
                int n = (w*4 + nbl) * 16 + l15;
                float vv = valid ? fast_silu(acc[mb][nbl][rr] + eb2v[nbl]) : 0.f;
                buf2[mm * 264 + n] = (f16)vv;
            }
        }
    __syncthreads();   // B4: e2 tile ready

    // ---- segmented reduction: thread t owns column t; src runs contiguous
    {
        int t = tid;
        float run = 0.f;
        int cur = srcr[0];
        for (int mm = 0; mm < 32; ++mm) {
            int s = srcr[mm];
            float v = (float)buf2[mm * 264 + t];
            if (s != cur) {
                if (cur >= 0) atomicAdd(aggsum + (size_t)cur * 256 + t, run);
                cur = s; run = v;
            } else run += v;
        }
        if (cur >= 0) atomicAdd(aggsum + (size_t)cur * 256 + t, run);
    }
}

// ---------------------------------------------------------------------------
// Node post: agg = aggsum / max(cnt,1); t = silu(Nh + agg@Wn1a + nb1);
// out = h + silu(t@Wn2 + nb2)
// ---------------------------------------------------------------------------
__global__ __launch_bounds__(256) void node_post_kernel(
    const float* __restrict__ aggsum, const int* __restrict__ cnt,
    const f16* __restrict__ Nh, const f16* __restrict__ Wn1a, const f16* __restrict__ Wn2,
    const float* __restrict__ nb1, const float* __restrict__ nb2,
    const float* __restrict__ h, float* __restrict__ out)
{
    __shared__ f16 T[64 * 264];
    int tid = threadIdx.x;
    int r = tid >> 2, c4 = tid & 3;
    int row = blockIdx.x * 64 + r;
    int rowc = min(row, N_NODES - 1);
    float inv = 1.f / fmaxf((float)cnt[rowc], 1.f);
    {
        const float* ap = aggsum + (size_t)rowc * 256 + c4 * 64;
        f16 av[64];
#pragma unroll
        for (int i = 0; i < 16; ++i) {
            float4 x = ((const float4*)ap)[i];
            av[4*i+0] = (f16)(x.x * inv);
            av[4*i+1] = (f16)(x.y * inv);
            av[4*i+2] = (f16)(x.z * inv);
            av[4*i+3] = (f16)(x.w * inv);
        }
        f16* dp = T + r * 264 + c4 * 64;
#pragma unroll
        for (int i = 0; i < 8; ++i) ((half8*)dp)[i] = ((half8*)av)[i];
    }
    __syncthreads();

    int lane = tid & 63, w = tid >> 6;
    int l15 = lane & 15, q = lane >> 4;
    const f32x4 z4 = {0.f, 0.f, 0.f, 0.f};

    f32x4 acc[4][4];
#pragma unroll
    for (int a = 0; a < 4; ++a)
#pragma unroll
        for (int b = 0; b < 4; ++b) acc[a][b] = z4;
    for (int ks = 0; ks < 8; ++ks) {
        half8 afr[4];
#pragma unroll
        for (int mb = 0; mb < 4; ++mb)
            afr[mb] = *(const half8*)(T + (mb*16 + l15) * 264 + ks*32 + q*8);
#pragma unroll
        for (int nbl = 0; nbl < 4; ++nbl) {
            int nb = w * 4 + nbl;
            half8 bfr = *(const half8*)(Wn1a + ((size_t)(nb*8 + ks) * 64 + lane) * 8);
#pragma unroll
            for (int mb = 0; mb < 4; ++mb)
                acc[mb][nbl] = __builtin_amdgcn_mfma_f32_16x16x32_f16(afr[mb], bfr, acc[mb][nbl], 0, 0, 0);
        }
    }
    __syncthreads();

#pragma unroll
    for (int mb = 0; mb < 4; ++mb)
#pragma unroll
        for (int rr = 0; rr < 4; ++rr) {
            int orow = blockIdx.x * 64 + mb*16 + q*4 + rr;
            int orc = min(orow, N_NODES - 1);
            const f16* np = Nh + (size_t)orc * 256;
            int mm = mb*16 + q*4 + rr;
#pragma unroll
            for (int nbl = 0; nbl < 4; ++nbl) {
                int n = (w*4 + nbl) * 16 + l15;
                float tv = fast_silu(acc[mb][nbl][rr] + (float)np[n] + nb1[n]);
                T[mm * 264 + n] = (f16)tv;
            }
        }
    __syncthreads();

    f32x4 acc2[4][4];
#pragma unroll
    for (int a = 0; a < 4; ++a)
#pragma unroll
        for (int b = 0; b < 4; ++b) acc2[a][b] = z4;
    for (int ks = 0; ks < 8; ++ks) {
        half8 afr[4];
#pragma unroll
        for (int mb = 0; mb < 4; ++mb)
            afr[mb] = *(const half8*)(T + (mb*16 + l15) * 264 + ks*32 + q*8);
#pragma unroll
        for (int nbl = 0; nbl < 4; ++nbl) {
            int nb = w * 4 + nbl;
            half8 bfr = *(const half8*)(Wn2 + ((size_t)(nb*8 + ks) * 64 + lane) * 8);
#pragma unroll
            for (int mb = 0; mb < 4; ++mb)
                acc2[mb][nbl] = __builtin_amdgcn_mfma_f32_16x16x32_f16(afr[mb], bfr, acc2[mb][nbl], 0, 0, 0);
        }
    }

#pragma unroll
    for (int mb = 0; mb < 4; ++mb)
#pragma unroll
        for (int rr = 0; rr < 4; ++rr) {
            int orow = blockIdx.x * 64 + mb*16 + q*4 + rr;
            if (orow < N_NODES) {
#pragma unroll
                for (int nbl = 0; nbl < 4; ++nbl) {
                    int n = (w*4 + nbl) * 16 + l15;
                    float ov = h[(size_t)orow * 256 + n] + fast_silu(acc2[mb][nbl][rr] + nb2[n]);
                    out[(size_t)orow * 256 + n] = ov;
                }
            }
        }
}

// ---------------------------------------------------------------------------
extern "C" void kernel_launch(void* const* d_in, const int* in_sizes, int n_in,
                              void* d_out, int out_size, void* d_ws, size_t ws_size,
                              hipStream_t stream) {
    const float* h          = (const float*)d_in[0];
    const float* lattices   = (const float*)d_in[2];
    const int*   edge_index = (const int*)d_in[3];
    const int*   edge2graph = (const int*)d_in[4];
    const float* frac_diff  = (const float*)d_in[5];
    const float* ln_gamma   = (const float*)d_in[6];
    const float* ln_beta    = (const float*)d_in[7];
    const float* eW1        = (const float*)d_in[8];
    const float* eb1        = (const float*)d_in[9];
    const float* eW2        = (const float*)d_in[10];
    const float* eb2        = (const float*)d_in[11];
    const float* nW1        = (const float*)d_in[12];
    const float* nb1        = (const float*)d_in[13];
    const float* nW2        = (const float*)d_in[14];
    const float* nb2        = (const float*)d_in[15];
    float* out = (float*)d_out;
    char* base = (char*)d_ws;

    // workspace layout (byte offsets)
    float* aggsum   = (float*)(base + 0);              // 51,200,000 B
    int*   cnt      = (int*)  (base + 51200000);       // 200,704
    int*   off      = (int*)  (base + 51400704);       // 200,704
    int*   tmp      = (int*)  (base + 51601408);       // 200,704
    int*   sorted_e = (int*)  (base + 51802112);       // 2,000,000
    f16*   latW16   = (f16*)  (base + 53802112);       // 65,536
    f16*   Hh1      = (f16*)  (base + 53867648);       // 25,600,000
    f16*   Hh2      = (f16*)  (base + 79467648);
    f16*   Nh       = (f16*)  (base + 105067648);
    f16*   packs    = (f16*)  (base + 130667648);
    f16* Wfd  = packs;            // 98,304 halfs (K=384)
    f16* Whi  = Wfd  + 98304;
    f16* Whj  = Whi  + 65536;
    f16* We2  = Whj  + 65536;
    f16* Wn1h = We2  + 65536;
    f16* Wn1a = Wn1h + 65536;
    f16* Wn2  = Wn1a + 65536;     // ends at byte 131,650,688
    if (ws_size < (size_t)131650688) return;

    // zero aggsum + cnt + off + tmp
    hipMemsetAsync(base, 0, (size_t)51802112, stream);

    pack_weight<<<48, 256, 0, stream>>>(eW1 + 521 * 256, Wfd, 12);
    pack_weight<<<32, 256, 0, stream>>>(eW1,             Whi, 8);
    pack_weight<<<32, 256, 0, stream>>>(eW1 + 256 * 256, Whj, 8);
    pack_weight<<<32, 256, 0, stream>>>(eW2,             We2, 8);
    pack_weight<<<32, 256, 0, stream>>>(nW1,             Wn1h, 8);
    pack_weight<<<32, 256, 0, stream>>>(nW1 + 256 * 256, Wn1a, 8);
    pack_weight<<<32, 256, 0, stream>>>(nW2,             Wn2, 8);
    prep_latw<<<G_GRAPHS, 256, 0, stream>>>(lattices, eW1, eb1, latW16);

    hist_kernel<<<(E_EDGES + 255) / 256, 256, 0, stream>>>(edge_index, cnt);
    scan_kernel<<<1, 1024, 0, stream>>>(cnt, off);
    pos_kernel<<<(E_EDGES + 255) / 256, 256, 0, stream>>>(edge_index, off, tmp, sorted_e);

    ln_gemm_kernel<<<(N_NODES + 63) / 64, 256, 0, stream>>>(
        h, ln_gamma, ln_beta, Whi, Whj, Wn1h, Hh1, Hh2, Nh);

    edge_kernel<<<(E_EDGES + 31) / 32, 256, 0, stream>>>(
        sorted_e, edge_index, edge2graph, frac_diff, Hh1, Hh2, latW16, Wfd, We2, eb2, aggsum);

    node_post_kernel<<<(N_NODES + 63) / 64, 256, 0, stream>>>(
        aggsum, cnt, Nh, Wn1a, Wn2, nb1, nb2, h, out);
}